// Round 12
// baseline (79.438 us; speedup 1.0000x reference)
//
#include <hip/hip_runtime.h>
#include <stdint.h>

#define NB 8
#define NI 16
#define NC 256
#define SH 512
#define NCH 84   // 256-pixel chunks per batch: 64 (L0) + 16 (L1) + 4 (L2)

typedef __bf16 bf16x8 __attribute__((ext_vector_type(8)));
typedef float f32x4 __attribute__((ext_vector_type(4)));
typedef uint32_t u32x4 __attribute__((ext_vector_type(4)));

// ws layout (bytes): small L2-resident accumulators, zeroed by zero_kernel
// each call (zero -> fused -> final in one stream = safe ordering).
static const size_t OFF_SSUM = 0;                                        // f32 [3][NB][NI][NC] = 393216 B
static const size_t OFF_CNT  = OFF_SSUM + (size_t)3 * NB * NI * NC * 4;  // int [3][NB][NI]    = 1536 B
static const size_t OFF_KEY  = OFF_CNT + (size_t)3 * NB * NI * 4;        // u64 [3][NB][NI]    = 3072 B
static const size_t WS_NEED  = OFF_KEY + (size_t)3 * NB * NI * 8;        // ~398 KB
static const int    ZERO_N4  = (int)(WS_NEED / 16);                      // float4 count (16-div)

__device__ __forceinline__ float4 ld4(const float* p) {
    return *reinterpret_cast<const float4*>(p);
}

// Zero the accumulator region (float4 stores; WS_NEED is 16B-divisible).
__global__ __launch_bounds__(256) void zero_kernel(float4* __restrict__ ws4) {
    const int i = blockIdx.x * 256 + threadIdx.x;
    if (i < ZERO_N4) ws4[i] = make_float4(0.f, 0.f, 0.f, 0.f);
}

// ---------------------------------------------------------------------------
// Fused per-chunk kernel. Block = 1024 thr = 16 waves; owns one 256-pixel
// chunk of one (b, level).
// KEY CHANGE vs R11: features are no longer gathered per-fragment (16 x 128B
// at 64KB stride per wave = DRAM-page scatter). The block stages a
// [64 ch][256 px] tile (64 KB LDS) per channel-quarter, where EACH WAVE LOADS
// 1 KB FULLY CONTIGUOUS of one channel row (streaming pattern). ds_write uses
// an XOR granule swizzle (slot = g ^ (row&15)) so the MFMA ds_read_b128
// fragments are 2-way-conflict-free (free, m136). Stage loads for quarter
// qc+1 are issued before the MFMA of qc (T14 issue-early / write-late);
// quarter-0 loads fly under phase A's scribble round trips.
// Phase A (4-way instance split, 2-instance pairs): quarter gi = tid>>8
//   handles instances gi*4..gi*4+3 for pixel tid&255. sr = exact 2x2 scribble
//   average (bilinear at integer scale, half-pixel); threshold folded to
//   s4 > 2. Nibbles merged to u16 in LDS. cnt: ballot-popcount -> LDS -> one
//   global atomicAdd per (block,i). Argmax key only when a whole wave sees
//   zero foreground (dead unless cnt==0 globally); key=(bits(sr)<<32)|(~pix).
// Phase B MFMA: wave w -> n-tile ntl=w&3 (16 channels) of each quarter,
//   k-pair kh=w>>2 (2 of 8 k-steps). The k-split partials for one output
//   channel merge through the global atomic accumulator (same mechanism as
//   the cross-block merge). C/D (m89): row=(lane>>4)*4+reg=instance,
//   col=lane&15=channel.
// ---------------------------------------------------------------------------
template<int W, int S, int P>
__device__ __forceinline__ void do_chunk(const float* __restrict__ f,
                                         const float* __restrict__ scr,
                                         float* __restrict__ ssum_lb,   // + (l*NB+b)*NI*NC
                                         int* __restrict__ cnt_lb,     // + (l*NB+b)*NI
                                         unsigned long long* __restrict__ key_lb,
                                         int b, int chunk, int tid,
                                         uint8_t* __restrict__ lmask8,
                                         uint16_t* __restrict__ lmask16,
                                         char* __restrict__ fbuf,
                                         int* __restrict__ lcnt,
                                         unsigned long long* __restrict__ lkey) {
    const int wave = tid >> 6;
    const int lane = tid & 63;
    const int kg = lane >> 4;     // k-subgroup 0..3 (8 px each within a k-step)
    const int cl = lane & 15;     // channel-in-tile (B/D) AND instance row (A)
    const int kb = chunk * 256;
    const float* fbase = f + (size_t)b * NC * P + kb;

    // stage-thread mapping: thread stages 4 granules (granule = float4 = 4 px)
    // n = s*1024 + tid; row rc = n>>6 (channel-in-quarter), g = n&63 (granule).
    // Wave = 64 consecutive n = one full 1 KB channel row. LDS slot: g^(rc&15).
    int s_rc[4], s_g[4];
    #pragma unroll
    for (int s = 0; s < 4; ++s) {
        const int n = s * 1024 + tid;
        s_rc[s] = n >> 6;
        s_g[s] = n & 63;
    }

    // ---- issue stage loads for quarter 0 (fly under phase A) ----
    float4 st[4];
    #pragma unroll
    for (int s = 0; s < 4; ++s)
        st[s] = ld4(fbase + (size_t)s_rc[s] * P + s_g[s] * 4);

    // ---- phase A: masks (2-instance pairs) ----
    const int gi = tid >> 8;        // instance quarter: instances gi*4..gi*4+3
    const int p = tid & 255;        // pixel within chunk
    const int pix = chunk * 256 + p;
    const int y = pix / W;
    const int x = pix - y * W;
    const int r0 = S * y + (S / 2 - 1);
    const int c0s = S * x + (S / 2 - 1);
    const float* sb = scr + ((size_t)b * NI + gi * 4) * (SH * SH) + (size_t)r0 * SH;
    unsigned int mword = 0;
    #pragma unroll
    for (int ii = 0; ii < 4; ii += 2) {
        float s4v[2];
        if constexpr (S == 4) {
            // c0s-1 = 4x -> 16B-aligned float4; cols 4x+1, 4x+2 are .y/.z
            float4 q0[2], q1[2];
            #pragma unroll
            for (int j = 0; j < 2; ++j) {
                const float* sp = sb + (size_t)(ii + j) * (SH * SH);
                q0[j] = ld4(sp + (c0s - 1));
                q1[j] = ld4(sp + SH + (c0s - 1));
            }
            #pragma unroll
            for (int j = 0; j < 2; ++j)
                s4v[j] = (q0[j].y + q0[j].z) + (q1[j].y + q1[j].z);
        } else {
            #pragma unroll
            for (int j = 0; j < 2; ++j) {
                const float* sp = sb + (size_t)(ii + j) * (SH * SH);
                s4v[j] = (sp[c0s] + sp[c0s + 1]) + (sp[SH + c0s] + sp[SH + c0s + 1]);
            }
        }
        #pragma unroll
        for (int j = 0; j < 2; ++j) {
            const int i = ii + j;
            const float s4 = s4v[j];
            bool bit = s4 > 2.0f;                 // == (0.25*s4 > 0.5)
            mword |= bit ? (1u << i) : 0u;
            unsigned long long bal = __ballot(bit);
            if (lane == 0) atomicAdd(&lcnt[gi * 4 + i], (int)__popcll(bal));
            if (bal == 0ull) {                    // whole wave empty -> argmax path
                unsigned int srb = __float_as_uint(0.25f * s4);
                unsigned int mx = srb;
                #pragma unroll
                for (int off = 1; off < 64; off <<= 1) {
                    unsigned int o = __shfl_xor(mx, off, 64);
                    mx = (o > mx) ? o : mx;
                }
                unsigned long long win = __ballot(srb == mx);
                if (lane == 0) {
                    int wl = __ffsll((unsigned long long)win) - 1;  // first = smallest pix
                    unsigned int wpix = (unsigned int)(chunk * 256 + (p & ~63) + wl);
                    unsigned long long key = (((unsigned long long)mx) << 32)
                                           | (unsigned long long)(0xFFFFFFFFu - wpix);
                    atomicMax(&lkey[gi * 4 + i], key);
                }
            }
        }
    }
    lmask8[gi * 256 + p] = (uint8_t)mword;   // 4-bit nibble per quarter
    __syncthreads();
    if (tid < 256)
        lmask16[tid] = (uint16_t)((unsigned)lmask8[tid]
                                | ((unsigned)lmask8[256 + tid] << 4)
                                | ((unsigned)lmask8[512 + tid] << 8)
                                | ((unsigned)lmask8[768 + tid] << 12));
    // ---- write staged quarter 0 into LDS (swizzled) ----
    #pragma unroll
    for (int s = 0; s < 4; ++s)
        *reinterpret_cast<float4*>(fbuf + s_rc[s] * 1024
                                   + ((s_g[s] ^ (s_rc[s] & 15)) * 16)) = st[s];
    __syncthreads();   // fbuf[q0] + lmask16 ready

    // ---- phase B: MFMA over 4 channel-quarters ----
    const int ntl = wave & 3;           // n-tile within quarter
    const int kh = wave >> 2;           // k-pair index (2 k-steps of 8)
    const int rc_r = ntl * 16 + cl;     // tile row this lane reads (rc_r&15==cl)
    const char* rbase = fbuf + rc_r * 1024;
    f32x4 acc[4];
    #pragma unroll
    for (int q = 0; q < 4; ++q) acc[q] = f32x4{0.f, 0.f, 0.f, 0.f};
    #pragma unroll
    for (int qc = 0; qc < 4; ++qc) {
        if (qc < 3) {   // issue next quarter's contiguous loads (T14)
            #pragma unroll
            for (int s = 0; s < 4; ++s)
                st[s] = ld4(fbase + (size_t)((qc + 1) * 64 + s_rc[s]) * P + s_g[s] * 4);
        }
        #pragma unroll
        for (int ks = 0; ks < 2; ++ks) {
            const int kglob = kh * 2 + ks;
            const int px = kglob * 32 + kg * 8;
            const uint4 wA = *reinterpret_cast<const uint4*>(lmask16 + px);
            u32x4 au;
            au.x = ((wA.x >> cl) & 0x10001u) * 0x3F80u;
            au.y = ((wA.y >> cl) & 0x10001u) * 0x3F80u;
            au.z = ((wA.z >> cl) & 0x10001u) * 0x3F80u;
            au.w = ((wA.w >> cl) & 0x10001u) * 0x3F80u;
            const bf16x8 av = __builtin_bit_cast(bf16x8, au);
            const int g0 = kglob * 8 + kg * 2;
            float4 v0 = *reinterpret_cast<const float4*>(rbase + ((g0 ^ cl) * 16));
            float4 v1 = *reinterpret_cast<const float4*>(rbase + (((g0 + 1) ^ cl) * 16));
            bf16x8 bv;
            bv[0] = (__bf16)v0.x; bv[1] = (__bf16)v0.y;
            bv[2] = (__bf16)v0.z; bv[3] = (__bf16)v0.w;
            bv[4] = (__bf16)v1.x; bv[5] = (__bf16)v1.y;
            bv[6] = (__bf16)v1.z; bv[7] = (__bf16)v1.w;
            acc[qc] = __builtin_amdgcn_mfma_f32_16x16x32_bf16(av, bv, acc[qc], 0, 0, 0);
        }
        __syncthreads();           // all waves done reading fbuf[qc]
        if (qc < 3) {
            #pragma unroll
            for (int s = 0; s < 4; ++s)
                *reinterpret_cast<float4*>(fbuf + s_rc[s] * 1024
                                           + ((s_g[s] ^ (s_rc[s] & 15)) * 16)) = st[s];
            __syncthreads();       // fbuf[qc+1] ready
        }
    }

    // ---- epilogue: merge k-split partials via the global atomic accumulator ----
    #pragma unroll
    for (int qc = 0; qc < 4; ++qc) {
        const int c = qc * 64 + ntl * 16 + cl;
        #pragma unroll
        for (int r = 0; r < 4; ++r)
            atomicAdd(&ssum_lb[(kg * 4 + r) * NC + c], acc[qc][r]);
    }
    if (tid < NI) {
        int v = lcnt[tid];
        if (v) atomicAdd(&cnt_lb[tid], v);                 // int add: deterministic
        unsigned long long k = lkey[tid];
        if (k) atomicMax(&key_lb[tid], k);                 // rare path only
    }
}

__global__ __launch_bounds__(1024, 8) void fused_kernel(const float* __restrict__ f0,
                                                        const float* __restrict__ f1,
                                                        const float* __restrict__ f2,
                                                        const float* __restrict__ scr,
                                                        float* __restrict__ ssum,
                                                        int* __restrict__ cnt,
                                                        unsigned long long* __restrict__ key) {
    __shared__ __align__(16) char fbuf[64 * 1024];   // [64 ch][64 granules x 16 B]
    __shared__ uint8_t lmask8[1024];
    __shared__ __align__(16) uint16_t lmask16[256];
    __shared__ int lcnt[NI];
    __shared__ unsigned long long lkey[NI];
    const int tid = threadIdx.x;
    const int b = blockIdx.y;
    const int bx = blockIdx.x;
    if (tid < NI) { lcnt[tid] = 0; lkey[tid] = 0ull; }
    __syncthreads();
    if (bx < 64) {
        const size_t o = (size_t)(0 * NB + b);
        do_chunk<128, 4, 16384>(f0, scr, ssum + o * NI * NC, cnt + o * NI, key + o * NI,
                                b, bx, tid, lmask8, lmask16, fbuf, lcnt, lkey);
    } else if (bx < 80) {
        const size_t o = (size_t)(1 * NB + b);
        do_chunk<64, 8, 4096>(f1, scr, ssum + o * NI * NC, cnt + o * NI, key + o * NI,
                              b, bx - 64, tid, lmask8, lmask16, fbuf, lcnt, lkey);
    } else {
        const size_t o = (size_t)(2 * NB + b);
        do_chunk<32, 16, 1024>(f2, scr, ssum + o * NI * NC, cnt + o * NI, key + o * NI,
                               b, bx - 80, tid, lmask8, lmask16, fbuf, lcnt, lkey);
    }
}

// ---------------------------------------------------------------------------
// Finalize (lite): 128 blocks x 256 thr; block = (b,i), thread = channel.
// out = mean over levels of (cnt>0 ? ssum/cnt : feat[argmax]).
// ---------------------------------------------------------------------------
__global__ __launch_bounds__(256) void final_kernel(const float* __restrict__ f0,
                                                    const float* __restrict__ f1,
                                                    const float* __restrict__ f2,
                                                    const int* __restrict__ cnt,
                                                    const unsigned long long* __restrict__ key,
                                                    const float* __restrict__ ssum,
                                                    float* __restrict__ out) {
    const int bi = blockIdx.x;       // b*NI + i
    const int c = threadIdx.x;
    const int b = bi >> 4;
    const float* fl[3] = {f0, f1, f2};
    const int Ps[3] = {16384, 4096, 1024};
    float r = 0.f;
    #pragma unroll
    for (int l = 0; l < 3; ++l) {
        const int cn = cnt[l * NB * NI + bi];
        float v;
        if (cn > 0) {
            v = ssum[((size_t)l * NB * NI + bi) * NC + c] / (float)cn;
        } else {
            unsigned int p = 0xFFFFFFFFu -
                (unsigned int)(key[l * NB * NI + bi] & 0xFFFFFFFFull);
            v = fl[l][((size_t)b * NC + c) * Ps[l] + p];
        }
        r += v;
    }
    out[(size_t)bi * NC + c] = r * (1.f / 3.f);
}

extern "C" void kernel_launch(void* const* d_in, const int* in_sizes, int n_in,
                              void* d_out, int out_size, void* d_ws, size_t ws_size,
                              hipStream_t stream) {
    const float* f0  = (const float*)d_in[0];   // [8,256,128,128]
    const float* f1  = (const float*)d_in[1];   // [8,256,64,64]
    const float* f2  = (const float*)d_in[2];   // [8,256,32,32]
    const float* scr = (const float*)d_in[3];   // [8,16,512,512]
    float* out = (float*)d_out;                 // [8,16,256]
    char* ws = (char*)d_ws;
    if (ws_size < WS_NEED) return;  // visible failure rather than corruption

    float* ssum = (float*)(ws + OFF_SSUM);
    int* cnt = (int*)(ws + OFF_CNT);
    unsigned long long* key = (unsigned long long*)(ws + OFF_KEY);

    zero_kernel<<<(ZERO_N4 + 255) / 256, 256, 0, stream>>>((float4*)ws);
    fused_kernel<<<dim3(NCH, NB), 1024, 0, stream>>>(f0, f1, f2, scr, ssum, cnt, key);
    final_kernel<<<NB * NI, NC, 0, stream>>>(f0, f1, f2, cnt, key, ssum, out);
}

// Round 13
// 61.651 us; speedup vs baseline: 1.2885x; 1.2885x over previous
//
#include <hip/hip_runtime.h>
#include <stdint.h>

#define NB 8
#define NI 16
#define NC 256
#define SH 512
#define NCH 84   // 256-pixel chunks per batch: 64 (L0) + 16 (L1) + 4 (L2)

typedef __bf16 bf16x8 __attribute__((ext_vector_type(8)));
typedef float f32x4 __attribute__((ext_vector_type(4)));
typedef uint32_t u32x4 __attribute__((ext_vector_type(4)));

// ws layout (bytes): small L2-resident accumulators, zeroed by zero_kernel
// each call (zero -> fused -> final in one stream = safe ordering).
static const size_t OFF_SSUM = 0;                                        // f32 [3][NB][NI][NC] = 393216 B
static const size_t OFF_CNT  = OFF_SSUM + (size_t)3 * NB * NI * NC * 4;  // int [3][NB][NI]    = 1536 B
static const size_t OFF_KEY  = OFF_CNT + (size_t)3 * NB * NI * 4;        // u64 [3][NB][NI]    = 3072 B
static const size_t WS_NEED  = OFF_KEY + (size_t)3 * NB * NI * 8;        // ~398 KB
static const int    ZERO_N4  = (int)(WS_NEED / 16);                      // float4 count (16-div)

__device__ __forceinline__ float4 ld4(const float* p) {
    return *reinterpret_cast<const float4*>(p);
}

// Zero the accumulator region (float4 stores; WS_NEED is 16B-divisible).
__global__ __launch_bounds__(256) void zero_kernel(float4* __restrict__ ws4) {
    const int i = blockIdx.x * 256 + threadIdx.x;
    if (i < ZERO_N4) ws4[i] = make_float4(0.f, 0.f, 0.f, 0.f);
}

// One MFMA k-step for this wave's single 16-channel n-tile: A-frag from mask
// words, B-frag packed from prefetched float4s (RNE v_cvt_pk_bf16_f32).
__device__ __forceinline__ void mfma_step1(const uint16_t* __restrict__ lmp, int ks, int cl,
                                           const float4 (&buf)[2], f32x4& a0) {
    const uint4 wA = *reinterpret_cast<const uint4*>(lmp + ks * 32);
    u32x4 au;
    au.x = ((wA.x >> cl) & 0x10001u) * 0x3F80u;
    au.y = ((wA.y >> cl) & 0x10001u) * 0x3F80u;
    au.z = ((wA.z >> cl) & 0x10001u) * 0x3F80u;
    au.w = ((wA.w >> cl) & 0x10001u) * 0x3F80u;
    const bf16x8 av = __builtin_bit_cast(bf16x8, au);
    bf16x8 bv;
    bv[0] = (__bf16)buf[0].x; bv[1] = (__bf16)buf[0].y;
    bv[2] = (__bf16)buf[0].z; bv[3] = (__bf16)buf[0].w;
    bv[4] = (__bf16)buf[1].x; bv[5] = (__bf16)buf[1].y;
    bv[6] = (__bf16)buf[1].z; bv[7] = (__bf16)buf[1].w;
    a0 = __builtin_amdgcn_mfma_f32_16x16x32_bf16(av, bv, a0, 0, 0, 0);
}

// ---------------------------------------------------------------------------
// Fused per-chunk kernel (R11 structure — best measured: 61.58 µs total).
// Block = 1024 thr = 16 waves; owns one 256-pixel chunk of one (b, level).
// Pipeline: issue feature ks=0,1 -> phase A (batched scribble loads) ->
//   ks=2,3 -> 8-step MFMA loop prefetching ks+4 (4-deep).
// Phase A (4-way instance split): quarter q = tid>>8 handles instances
//   q*4..q*4+3 for pixel tid&255; batch-loaded 2x2 scribble samples, then
//   compare/ballot on registers. sr = exact 2x2 average (bilinear at integer
//   scale, half-pixel centers); threshold folded to s4 > 2. Nibbles merged
//   to u16 masks in LDS. cnt: ballot-popcount -> LDS -> ONE global atomicAdd
//   per (block, i) (integer = deterministic). Argmax key only when a whole
//   wave sees zero foreground (dead unless cnt==0 globally); global atomicMax
//   skipped when key==0 (common case). key=(bits(sr)<<32)|(~pix).
// Phase B: ssum[i,c] += sum_p mask[i,p]*feat[c,p] via mfma_f32_16x16x32_bf16.
//   Wave w = channels w*16..w*16+15; K = 256 chunk pixels = 8 k-steps.
//   C/D (m89): row=(lane>>4)*4+reg=instance, col=lane&15=channel. Tile
//   accumulated into the small L2-resident global accumulator via atomicAdd
//   (4096 distinct addresses per block; fp-order nondeterminism ~1 ulp).
// ---------------------------------------------------------------------------
template<int W, int S, int P>
__device__ __forceinline__ void do_chunk(const float* __restrict__ f,
                                         const float* __restrict__ scr,
                                         float* __restrict__ ssum_lb,   // + (l*NB+b)*NI*NC
                                         int* __restrict__ cnt_lb,     // + (l*NB+b)*NI
                                         unsigned long long* __restrict__ key_lb,
                                         int b, int chunk, int tid,
                                         uint8_t* __restrict__ lmask8,
                                         uint16_t* __restrict__ lmask16,
                                         int* __restrict__ lcnt,
                                         unsigned long long* __restrict__ lkey) {
    // ---- phase-B addressing + early prefetch of ks=0,1 ----
    const int wave = tid >> 6;
    const int lane = tid & 63;
    const int kg = lane >> 4;   // k-subgroup 0..3
    const int cl = lane & 15;   // channel-within-tile (B/D) AND instance row (A)
    const int c0 = wave * 16;   // one 16-channel n-tile per wave
    const int kb = chunk * 256;
    const float* fp0 = f + ((size_t)b * NC + c0 + cl) * P + kb + kg * 8;
    float4 buf[4][2];
    #pragma unroll
    for (int k = 0; k < 2; ++k) {
        buf[k][0] = ld4(fp0 + k * 32);
        buf[k][1] = ld4(fp0 + k * 32 + 4);
    }

    // ---- phase A: batch-load 4 instances' samples, then resolve ----
    const int gi = tid >> 8;        // instance quarter: instances gi*4..gi*4+3
    const int p = tid & 255;        // pixel within chunk
    const int pix = chunk * 256 + p;
    const int y = pix / W;
    const int x = pix - y * W;
    const int r0 = S * y + (S / 2 - 1);
    const int c0s = S * x + (S / 2 - 1);
    const float* sb = scr + ((size_t)b * NI + gi * 4) * (SH * SH) + (size_t)r0 * SH;
    float s4v[4];
    if constexpr (S == 4) {
        // c0s-1 = 4x -> 16B-aligned float4; cols 4x+1, 4x+2 are .y/.z
        float4 q0[4], q1[4];
        #pragma unroll
        for (int i = 0; i < 4; ++i) {
            const float* sp = sb + (size_t)i * (SH * SH);
            q0[i] = ld4(sp + (c0s - 1));
            q1[i] = ld4(sp + SH + (c0s - 1));
        }
        #pragma unroll
        for (int i = 0; i < 4; ++i)
            s4v[i] = (q0[i].y + q0[i].z) + (q1[i].y + q1[i].z);
    } else {
        float qa[4], qb[4], qc[4], qd[4];
        #pragma unroll
        for (int i = 0; i < 4; ++i) {
            const float* sp = sb + (size_t)i * (SH * SH);
            qa[i] = sp[c0s];
            qb[i] = sp[c0s + 1];
            qc[i] = sp[SH + c0s];
            qd[i] = sp[SH + c0s + 1];
        }
        #pragma unroll
        for (int i = 0; i < 4; ++i)
            s4v[i] = (qa[i] + qb[i]) + (qc[i] + qd[i]);
    }
    unsigned int mword = 0;
    #pragma unroll
    for (int i = 0; i < 4; ++i) {
        const float s4 = s4v[i];
        bool bit = s4 > 2.0f;                 // == (0.25*s4 > 0.5)
        mword |= bit ? (1u << i) : 0u;
        unsigned long long bal = __ballot(bit);
        if (lane == 0) atomicAdd(&lcnt[gi * 4 + i], (int)__popcll(bal));
        if (bal == 0ull) {                    // whole wave empty -> argmax path
            unsigned int srb = __float_as_uint(0.25f * s4);
            unsigned int mx = srb;
            #pragma unroll
            for (int off = 1; off < 64; off <<= 1) {
                unsigned int o = __shfl_xor(mx, off, 64);
                mx = (o > mx) ? o : mx;
            }
            unsigned long long win = __ballot(srb == mx);
            if (lane == 0) {
                int wl = __ffsll((unsigned long long)win) - 1;  // first = smallest pix
                unsigned int wpix = (unsigned int)(chunk * 256 + (p & ~63) + wl);
                unsigned long long key = (((unsigned long long)mx) << 32)
                                       | (unsigned long long)(0xFFFFFFFFu - wpix);
                atomicMax(&lkey[gi * 4 + i], key);
            }
        }
    }
    lmask8[gi * 256 + p] = (uint8_t)mword;   // 4-bit nibble per quarter
    __syncthreads();
    if (tid < 256)
        lmask16[tid] = (uint16_t)((unsigned)lmask8[tid]
                                | ((unsigned)lmask8[256 + tid] << 4)
                                | ((unsigned)lmask8[512 + tid] << 8)
                                | ((unsigned)lmask8[768 + tid] << 12));
    __syncthreads();

    // ---- phase B: 4-deep pipelined MFMA over 8 k-steps ----
    #pragma unroll
    for (int k = 2; k < 4; ++k) {           // complete the 4-deep prologue
        buf[k][0] = ld4(fp0 + k * 32);
        buf[k][1] = ld4(fp0 + k * 32 + 4);
    }
    const uint16_t* lmp = lmask16 + kg * 8;
    f32x4 acc = {0.f, 0.f, 0.f, 0.f};
    #pragma unroll
    for (int ks = 0; ks < 8; ++ks) {
        mfma_step1(lmp, ks, cl, buf[ks & 3], acc);
        if (ks + 4 < 8) {                    // refill the slot just consumed
            buf[ks & 3][0] = ld4(fp0 + (ks + 4) * 32);
            buf[ks & 3][1] = ld4(fp0 + (ks + 4) * 32 + 4);
        }
    }
    const int c = c0 + cl;
    #pragma unroll
    for (int r = 0; r < 4; ++r)
        atomicAdd(&ssum_lb[(kg * 4 + r) * NC + c], acc[r]);

    // ---- flush per-block cnt/key (off the MFMA critical path) ----
    if (tid < NI) {
        int v = lcnt[tid];
        if (v) atomicAdd(&cnt_lb[tid], v);                 // int add: deterministic
        unsigned long long k = lkey[tid];
        if (k) atomicMax(&key_lb[tid], k);                 // rare path only
    }
}

__global__ __launch_bounds__(1024, 8) void fused_kernel(const float* __restrict__ f0,
                                                        const float* __restrict__ f1,
                                                        const float* __restrict__ f2,
                                                        const float* __restrict__ scr,
                                                        float* __restrict__ ssum,
                                                        int* __restrict__ cnt,
                                                        unsigned long long* __restrict__ key) {
    __shared__ uint8_t lmask8[1024];
    __shared__ __align__(16) uint16_t lmask16[256];
    __shared__ int lcnt[NI];
    __shared__ unsigned long long lkey[NI];
    const int tid = threadIdx.x;
    const int b = blockIdx.y;
    const int bx = blockIdx.x;
    if (tid < NI) { lcnt[tid] = 0; lkey[tid] = 0ull; }
    __syncthreads();
    if (bx < 64) {
        const size_t o = (size_t)(0 * NB + b);
        do_chunk<128, 4, 16384>(f0, scr, ssum + o * NI * NC, cnt + o * NI, key + o * NI,
                                b, bx, tid, lmask8, lmask16, lcnt, lkey);
    } else if (bx < 80) {
        const size_t o = (size_t)(1 * NB + b);
        do_chunk<64, 8, 4096>(f1, scr, ssum + o * NI * NC, cnt + o * NI, key + o * NI,
                              b, bx - 64, tid, lmask8, lmask16, lcnt, lkey);
    } else {
        const size_t o = (size_t)(2 * NB + b);
        do_chunk<32, 16, 1024>(f2, scr, ssum + o * NI * NC, cnt + o * NI, key + o * NI,
                               b, bx - 80, tid, lmask8, lmask16, lcnt, lkey);
    }
}

// ---------------------------------------------------------------------------
// Finalize (lite): 128 blocks x 256 thr; block = (b,i), thread = channel.
// out = mean over levels of (cnt>0 ? ssum/cnt : feat[argmax]).
// ---------------------------------------------------------------------------
__global__ __launch_bounds__(256) void final_kernel(const float* __restrict__ f0,
                                                    const float* __restrict__ f1,
                                                    const float* __restrict__ f2,
                                                    const int* __restrict__ cnt,
                                                    const unsigned long long* __restrict__ key,
                                                    const float* __restrict__ ssum,
                                                    float* __restrict__ out) {
    const int bi = blockIdx.x;       // b*NI + i
    const int c = threadIdx.x;
    const int b = bi >> 4;
    const float* fl[3] = {f0, f1, f2};
    const int Ps[3] = {16384, 4096, 1024};
    float r = 0.f;
    #pragma unroll
    for (int l = 0; l < 3; ++l) {
        const int cn = cnt[l * NB * NI + bi];
        float v;
        if (cn > 0) {
            v = ssum[((size_t)l * NB * NI + bi) * NC + c] / (float)cn;
        } else {
            unsigned int p = 0xFFFFFFFFu -
                (unsigned int)(key[l * NB * NI + bi] & 0xFFFFFFFFull);
            v = fl[l][((size_t)b * NC + c) * Ps[l] + p];
        }
        r += v;
    }
    out[(size_t)bi * NC + c] = r * (1.f / 3.f);
}

extern "C" void kernel_launch(void* const* d_in, const int* in_sizes, int n_in,
                              void* d_out, int out_size, void* d_ws, size_t ws_size,
                              hipStream_t stream) {
    const float* f0  = (const float*)d_in[0];   // [8,256,128,128]
    const float* f1  = (const float*)d_in[1];   // [8,256,64,64]
    const float* f2  = (const float*)d_in[2];   // [8,256,32,32]
    const float* scr = (const float*)d_in[3];   // [8,16,512,512]
    float* out = (float*)d_out;                 // [8,16,256]
    char* ws = (char*)d_ws;
    if (ws_size < WS_NEED) return;  // visible failure rather than corruption

    float* ssum = (float*)(ws + OFF_SSUM);
    int* cnt = (int*)(ws + OFF_CNT);
    unsigned long long* key = (unsigned long long*)(ws + OFF_KEY);

    zero_kernel<<<(ZERO_N4 + 255) / 256, 256, 0, stream>>>((float4*)ws);
    fused_kernel<<<dim3(NCH, NB), 1024, 0, stream>>>(f0, f1, f2, scr, ssum, cnt, key);
    final_kernel<<<NB * NI, NC, 0, stream>>>(f0, f1, f2, cnt, key, ssum, out);
}